// Round 13
// baseline (979.158 us; speedup 1.0000x reference)
//
#include <hip/hip_runtime.h>
#include <cstdint>
#include <cstddef>

#define BB 256
#define TT 250
#define DIN 700
#define H1 256
#define H2 256
#define DOUT 20
#define BJ0 0.01f
#define BETAC 1.8f
#define IQSCALE 3.814697265625e-06f   // 2^-18

typedef float f32x4 __attribute__((ext_vector_type(4)));
typedef short s16x4 __attribute__((ext_vector_type(4)));
typedef int   i32x4 __attribute__((ext_vector_type(4)));

// ---------------------------------------------------------------------------
// Workspace layout (bytes) — identical to R9/R12:
//   Bh   [256*704] i8  @ 0         hi8 of q18(w_i2h1), k-pad 700..703 = 0
//   Bl   [256*704] i8  @ 180224    lo8 (q = 256*hi + lo, exact)
//   sT11 [256*256] s16 @ 360448    sT11[d*256+h] = q18(w_h12h1[h][d])
//   sT12 [256*256] s16 @ 491520    q18(w_h12h2[h][d])
//   sT22 [256*256] s16 @ 622592    q18(w_h22h2[h][d])
//   w2o  [256*20]  f32 @ 753664    w2o[j*20+o] = w_h2o[o][j]
//   Xp   [64000*256] f32 @ 774144
//   Mo   [256*250*20] f32 @ 66310144
// ---------------------------------------------------------------------------
#define COFF_BL  180224
#define SOFF_T11 180224
#define SOFF_T12 245760
#define SOFF_T22 311296
#define FOFF_W2O 188416
#define FOFF_XP  193536
#define FOFF_MO  16577536
#define N_TRANS  381952

__device__ __forceinline__ short q18(float w) {
    float s = w * 262144.0f;
    s = fminf(fmaxf(s, -32767.0f), 32767.0f);
    return (short)__float2int_rn(s);
}

__global__ void transpose_all_k(const float* __restrict__ w_i2h1,
                                const float* __restrict__ w_h12h1,
                                const float* __restrict__ w_h12h2,
                                const float* __restrict__ w_h22h2,
                                const float* __restrict__ w_h2o,
                                signed char* __restrict__ cws,
                                short* __restrict__ sws,
                                float* __restrict__ fws) {
    int i = blockIdx.x * blockDim.x + threadIdx.x;
    if (i < 180224) {               // Bh/Bl: [h=0..255][k=0..703]
        int h = i / 704, k = i - h * 704;
        int q = (k < DIN) ? (int)q18(w_i2h1[h * DIN + k]) : 0;
        q = q > 32639 ? 32639 : (q < -32640 ? -32640 : q);  // keep hi8 in range
        int hi = (q + 128) >> 8;
        int lo = q - (hi << 8);
        cws[i] = (signed char)hi;
        cws[COFF_BL + i] = (signed char)lo;
        return;
    }
    i -= 180224;
    if (i < 65536) { int d = i >> 8, h = i & 255;
        sws[SOFF_T11 + i] = q18(w_h12h1[h * H1 + d]); return; }
    i -= 65536;
    if (i < 65536) { int d = i >> 8, h = i & 255;
        sws[SOFF_T12 + i] = q18(w_h12h2[h * H1 + d]); return; }
    i -= 65536;
    if (i < 65536) { int d = i >> 8, h = i & 255;
        sws[SOFF_T22 + i] = q18(w_h22h2[h * H2 + d]); return; }
    i -= 65536;
    if (i < 5120)  { int j = i / 20, o = i % 20;
        fws[FOFF_W2O + i] = w_h2o[o * H2 + j]; return; }
}

// ---------------------------------------------------------------------------
// xgemm_k: Xp = x @ W^T + b_h1 via two exact i8 MFMA GEMMs (unchanged).
// ---------------------------------------------------------------------------
__global__ __launch_bounds__(256) void xgemm_k(const float* __restrict__ x,
                                               const signed char* __restrict__ Bh,
                                               const signed char* __restrict__ Bl,
                                               const float* __restrict__ b_h1,
                                               float* __restrict__ Xp) {
    const int t    = threadIdx.x;
    const int lane = t & 63;
    const int w    = t >> 6;             // wave 0..3 -> cols [64w, 64w+64)
    const int m0   = blockIdx.x * 32;

    __shared__ __align__(16) signed char Asub[32 * 720];
    __shared__ __align__(16) signed char Bhs[256 * 80];
    __shared__ __align__(16) signed char Bls[256 * 80];

    #pragma unroll
    for (int it = 0; it < 22; ++it) {
        int flat = it * 256 + t;
        int row  = flat / 176;
        int c4   = flat - row * 176;
        unsigned int pk = 0u;
        if (c4 < 175) {
            const float* xr = x + (size_t)(m0 + row) * DIN;
            float4 f = *(const float4*)(xr + (c4 << 2));
            pk = (f.x != 0.f ? 1u : 0u)
               | (f.y != 0.f ? 1u : 0u) << 8
               | (f.z != 0.f ? 1u : 0u) << 16
               | (f.w != 0.f ? 1u : 0u) << 24;
        }
        *(unsigned int*)(Asub + row * 720 + (c4 << 2)) = pk;
    }

    i32x4 acch[2][4], accl[2][4];
    #pragma unroll
    for (int mt = 0; mt < 2; ++mt)
        #pragma unroll
        for (int nt = 0; nt < 4; ++nt) {
            acch[mt][nt] = (i32x4){0, 0, 0, 0};
            accl[mt][nt] = (i32x4){0, 0, 0, 0};
        }

    const int arow  = lane & 15;
    const int kg16  = (lane >> 4) << 4;
    const int bcol0 = w << 6;

    for (int ks = 0; ks < 11; ++ks) {
        __syncthreads();
        #pragma unroll
        for (int it2 = 0; it2 < 4; ++it2) {
            int row = it2 * 64 + (t >> 2);
            int ch  = (t & 3) << 4;
            int go  = row * 704 + ks * 64 + ch;
            *(int4*)(Bhs + row * 80 + ch) = *(const int4*)(Bh + go);
            *(int4*)(Bls + row * 80 + ch) = *(const int4*)(Bl + go);
        }
        __syncthreads();

        const int ko = ks * 64 + kg16;
        i32x4 a0 = *(const i32x4*)(Asub + arow * 720 + ko);
        i32x4 a1 = *(const i32x4*)(Asub + (16 + arow) * 720 + ko);
        #pragma unroll
        for (int nt = 0; nt < 4; ++nt) {
            const int bb = (bcol0 + nt * 16 + arow) * 80 + kg16;
            i32x4 bhf = *(const i32x4*)(Bhs + bb);
            i32x4 blf = *(const i32x4*)(Bls + bb);
            acch[0][nt] = __builtin_amdgcn_mfma_i32_16x16x64_i8(a0, bhf, acch[0][nt], 0, 0, 0);
            acch[1][nt] = __builtin_amdgcn_mfma_i32_16x16x64_i8(a1, bhf, acch[1][nt], 0, 0, 0);
            accl[0][nt] = __builtin_amdgcn_mfma_i32_16x16x64_i8(a0, blf, accl[0][nt], 0, 0, 0);
            accl[1][nt] = __builtin_amdgcn_mfma_i32_16x16x64_i8(a1, blf, accl[1][nt], 0, 0, 0);
        }
    }

    const int crb = (lane >> 4) << 2;
    #pragma unroll
    for (int nt = 0; nt < 4; ++nt) {
        int col = bcol0 + nt * 16 + arow;
        float bias = b_h1[col];
        #pragma unroll
        for (int mt = 0; mt < 2; ++mt) {
            #pragma unroll
            for (int r = 0; r < 4; ++r) {
                int row = m0 + mt * 16 + crb + r;
                int ir = (acch[mt][nt][r] << 8) + accl[mt][nt][r];
                __builtin_nontemporal_store(bias + (float)ir * IQSCALE,
                                            Xp + (size_t)row * H1 + col);
            }
        }
    }
}

// ---------------------------------------------------------------------------
// 4-column gather helpers (proven in R12): lane owns cols c0..c0+3; per
// entry e one s16x4 load at T + e*256 (T pre-offset by c0). 8 entries per
// wait group; count-guarded tail (lists zero-init -> stale reads in-bounds).
// ---------------------------------------------------------------------------
__device__ __forceinline__ void add8v(const short* __restrict__ T,
                                      const int* __restrict__ L, int off,
                                      int* a) {
    int4 ea = *(const int4*)(L + off);
    int4 eb = *(const int4*)(L + off + 4);
    s16x4 w0 = *(const s16x4*)(T + ((size_t)ea.x << 8));
    s16x4 w1 = *(const s16x4*)(T + ((size_t)ea.y << 8));
    s16x4 w2 = *(const s16x4*)(T + ((size_t)ea.z << 8));
    s16x4 w3 = *(const s16x4*)(T + ((size_t)ea.w << 8));
    s16x4 w4 = *(const s16x4*)(T + ((size_t)eb.x << 8));
    s16x4 w5 = *(const s16x4*)(T + ((size_t)eb.y << 8));
    s16x4 w6 = *(const s16x4*)(T + ((size_t)eb.z << 8));
    s16x4 w7 = *(const s16x4*)(T + ((size_t)eb.w << 8));
    a[0] += ((w0.x + w1.x) + (w2.x + w3.x)) + ((w4.x + w5.x) + (w6.x + w7.x));
    a[1] += ((w0.y + w1.y) + (w2.y + w3.y)) + ((w4.y + w5.y) + (w6.y + w7.y));
    a[2] += ((w0.z + w1.z) + (w2.z + w3.z)) + ((w4.z + w5.z) + (w6.z + w7.z));
    a[3] += ((w0.w + w1.w) + (w2.w + w3.w)) + ((w4.w + w5.w) + (w6.w + w7.w));
}

__device__ __forceinline__ void tailv(const short* __restrict__ T,
                                      const int* __restrict__ L, int done,
                                      int rem, int* a) {
    if (rem >= 4) {
        int4 e = *(const int4*)(L + done);
        s16x4 w0 = *(const s16x4*)(T + ((size_t)e.x << 8));
        s16x4 w1 = *(const s16x4*)(T + ((size_t)e.y << 8));
        s16x4 w2 = *(const s16x4*)(T + ((size_t)e.z << 8));
        s16x4 w3 = *(const s16x4*)(T + ((size_t)e.w << 8));
        a[0] += (w0.x + w1.x) + (w2.x + w3.x);
        a[1] += (w0.y + w1.y) + (w2.y + w3.y);
        a[2] += (w0.z + w1.z) + (w2.z + w3.z);
        a[3] += (w0.w + w1.w) + (w2.w + w3.w);
        done += 4; rem -= 4;
    }
    if (rem) {
        int4 e = *(const int4*)(L + done);
        s16x4 w0 = *(const s16x4*)(T + ((size_t)e.x << 8));
        a[0] += w0.x; a[1] += w0.y; a[2] += w0.z; a[3] += w0.w;
        if (rem > 1) {
            s16x4 w1 = *(const s16x4*)(T + ((size_t)e.y << 8));
            a[0] += w1.x; a[1] += w1.y; a[2] += w1.z; a[3] += w1.w;
        }
        if (rem > 2) {
            s16x4 w2 = *(const s16x4*)(T + ((size_t)e.z << 8));
            a[0] += w2.x; a[1] += w2.y; a[2] += w2.z; a[3] += w2.w;
        }
    }
}

__device__ __forceinline__ void add8f(const float* __restrict__ T,
                                      const int* __restrict__ L, int off,
                                      float& acc) {
    int4 ea = *(const int4*)(L + off);
    int4 eb = *(const int4*)(L + off + 4);
    acc += T[ea.x * DOUT]; acc += T[ea.y * DOUT];
    acc += T[ea.z * DOUT]; acc += T[ea.w * DOUT];
    acc += T[eb.x * DOUT]; acc += T[eb.y * DOUT];
    acc += T[eb.z * DOUT]; acc += T[eb.w * DOUT];
}

__device__ __forceinline__ void tailf(const float* __restrict__ T,
                                      const int* __restrict__ L, int done,
                                      int rem, float& acc) {
    if (rem >= 4) {
        int4 e = *(const int4*)(L + done);
        acc += T[e.x * DOUT]; acc += T[e.y * DOUT];
        acc += T[e.z * DOUT]; acc += T[e.w * DOUT];
        done += 4; rem -= 4;
    }
    if (rem) {
        int4 e = *(const int4*)(L + done);
        acc += T[e.x * DOUT];
        if (rem > 1) acc += T[e.y * DOUT];
        if (rem > 2) acc += T[e.z * DOUT];
    }
}

// ---------------------------------------------------------------------------
// rec_k: ONE WAVE per batch element (64 threads, 256 blocks). NO barriers in
// the loop — wave-synchronous execution:
//   - lane owns L1 cols 4l..4l+3 AND L2 cols 4l..4l+3; lanes 0..19 own one
//     output column each.
//   - list counts live in REGISTERS (ballot popcounts are wave-uniform) —
//     the lcnt LDS read, first link of R9's chain, is gone.
//   - per tick: interleaved T11/T12/T22 gathers over lst1/lst2[cur] (all
//     loads co-resident in flight) -> in-register LIF updates + ballots ->
//     intra-wave prefix scatter into lst*[nxt] -> lgkmcnt(0) (DS ops are
//     in-order per wave; the wait makes write->read airtight).
//   Tick offsets and integer q18 sums identical to R12 -> spike path
//   bit-exact. LDS: 20480 + 2*1024*2 = 24,576 B.
// ---------------------------------------------------------------------------
__global__ __launch_bounds__(64) void rec_k(
    const float* __restrict__ Xp,
    const short* __restrict__ sT11, const short* __restrict__ sT12,
    const short* __restrict__ sT22, const float* __restrict__ wT2o,
    const float* __restrict__ b_h2, const float* __restrict__ b_o,
    const float* __restrict__ tau_adp_h1, const float* __restrict__ tau_adp_h2,
    const float* __restrict__ tau_m_h1, const float* __restrict__ tau_m_h2,
    const float* __restrict__ tau_m_o,
    float* __restrict__ Mo) {
    const int lane = threadIdx.x;        // 0..63
    const int c0   = lane << 2;          // first of 4 owned columns (both layers)
    const int b    = blockIdx.x;
    const float* __restrict__ XpB = Xp + (size_t)b * TT * H1;
    float* __restrict__ MoB = Mo + (size_t)b * TT * DOUT;

    __shared__ __align__(16) float w2oL[5120];     // 20 KB [j][0..19]
    __shared__ __align__(16) int lst1s[2][256];
    __shared__ __align__(16) int lst2s[2][256];

    // one-time staging
    for (int k = lane; k < 5120; k += 64) w2oL[k] = wT2o[k];
    for (int k = lane; k < 256; k += 64) {
        lst1s[0][k] = 0; lst1s[1][k] = 0;
        lst2s[0][k] = 0; lst2s[1][k] = 0;
    }

    // per-lane constants (4 columns of each layer)
    float a1c[4], r1c[4], a2c[4], r2c[4], inb[4];
    #pragma unroll
    for (int s = 0; s < 4; ++s) {
        a1c[s] = expf(-1.0f / tau_m_h1[c0 + s]);
        r1c[s] = expf(-1.0f / tau_adp_h1[c0 + s]);
        a2c[s] = expf(-1.0f / tau_m_h2[c0 + s]);
        r2c[s] = expf(-1.0f / tau_adp_h2[c0 + s]);
        inb[s] = b_h2[c0 + s];
    }
    float alpo = 0.f, bov = 0.f;
    if (lane < DOUT) { alpo = expf(-1.0f / tau_m_o[lane]); bov = b_o[lane]; }

    float mem1[4] = {0.f, 0.f, 0.f, 0.f};
    float bb1[4]  = {BJ0, BJ0, BJ0, BJ0};
    float spk1[4] = {0.f, 0.f, 0.f, 0.f};
    float mem2[4] = {0.f, 0.f, 0.f, 0.f};
    float bb2[4]  = {BJ0, BJ0, BJ0, BJ0};
    float spk2[4] = {0.f, 0.f, 0.f, 0.f};
    float memo = 0.f;
    int t1c = 0, t2c = 0;                 // list counts, REGISTER-resident

    f32x4 xp_cur = *(const f32x4*)(XpB + c0);
    __syncthreads();                       // staging visible (once)

    for (int i = 0; i <= TT + 1; ++i) {
        const int cur = i & 1, nxt = cur ^ 1;

        f32x4 xp_nxt = (f32x4){0.f, 0.f, 0.f, 0.f};
        if (i + 1 < TT)
            xp_nxt = *(const f32x4*)(XpB + (size_t)(i + 1) * H1 + c0);

        const int* __restrict__ L1l = lst1s[cur];
        const int* __restrict__ L2l = lst2s[cur];
        const bool d1 = (i < TT);
        const bool d2 = (i >= 1 && i <= TT);
        const int nb1 = t1c >> 3, rem1 = t1c & 7;
        const int nb2 = t2c >> 3, rem2 = t2c & 7;

        int A11[4] = {0, 0, 0, 0};
        int A12[4] = {0, 0, 0, 0};
        int A22[4] = {0, 0, 0, 0};
        float ao = 0.f;

        // ---- interleaved gathers: all three tables' chunks issue together
        {
            const short* cT11 = sT11 + c0;
            const short* cT12 = sT12 + c0;
            const short* cT22 = sT22 + c0;
            const int nbm = nb1 > nb2 ? nb1 : nb2;
            for (int kk = 0; kk < nbm; ++kk) {
                if (d1 && kk < nb1) add8v(cT11, L1l, kk << 3, A11);
                if (d2 && kk < nb1) add8v(cT12, L1l, kk << 3, A12);
                if (d2 && kk < nb2) add8v(cT22, L2l, kk << 3, A22);
            }
            if (d1) tailv(cT11, L1l, nb1 << 3, rem1, A11);
            if (d2) {
                tailv(cT12, L1l, nb1 << 3, rem1, A12);
                tailv(cT22, L2l, nb2 << 3, rem2, A22);
            }
        }
        if (lane < DOUT && i >= 2) {       // output gather (LDS w2o)
            const float* colO = w2oL + lane;
            for (int kk = 0; kk < nb2; ++kk) add8f(colO, L2l, kk << 3, ao);
            tailf(colO, L2l, nb2 << 3, rem2, ao);
        }

        const unsigned long long below = (1ull << lane) - 1ull;

        // ---- U1(step i): update, ballot, prefix-scatter into lst1[nxt] ----
        if (d1) {
            unsigned long long Ms[4];
            #pragma unroll
            for (int s = 0; s < 4; ++s) {
                float r1 = (float)A11[s] * IQSCALE;
                bb1[s]  = r1c[s] * bb1[s] + BETAC * (1.f - r1c[s]) * spk1[s];
                mem1[s] = mem1[s] * a1c[s] - bb1[s] * spk1[s]
                        + (1.f - a1c[s]) * (xp_cur[s] + r1);
                float ns = (mem1[s] - bb1[s] - BJ0) > 0.f ? 1.f : 0.f;
                spk1[s] = ns;
                Ms[s] = __ballot(ns != 0.f ? 1 : 0);
            }
            int p0 = __popcll(Ms[0]), p1 = __popcll(Ms[1]);
            int p2 = __popcll(Ms[2]), p3 = __popcll(Ms[3]);
            int o1 = p0, o2 = p0 + p1, o3 = p0 + p1 + p2;
            if (spk1[0] != 0.f) lst1s[nxt][__popcll(Ms[0] & below)]      = c0;
            if (spk1[1] != 0.f) lst1s[nxt][o1 + __popcll(Ms[1] & below)] = c0 + 1;
            if (spk1[2] != 0.f) lst1s[nxt][o2 + __popcll(Ms[2] & below)] = c0 + 2;
            if (spk1[3] != 0.f) lst1s[nxt][o3 + __popcll(Ms[3] & below)] = c0 + 3;
            t1c = o3 + p3;
        } else {
            t1c = 0;
        }

        // ---- U2(step i-1): update, ballot, prefix-scatter into lst2[nxt] ----
        if (d2) {
            unsigned long long Ms[4];
            #pragma unroll
            for (int s = 0; s < 4; ++s) {
                float r23 = (float)(A12[s] + A22[s]) * IQSCALE;
                bb2[s]  = r2c[s] * bb2[s] + BETAC * (1.f - r2c[s]) * spk2[s];
                mem2[s] = mem2[s] * a2c[s] - bb2[s] * spk2[s]
                        + (1.f - a2c[s]) * (inb[s] + r23);
                float ns = (mem2[s] - bb2[s] - BJ0) > 0.f ? 1.f : 0.f;
                spk2[s] = ns;
                Ms[s] = __ballot(ns != 0.f ? 1 : 0);
            }
            int p0 = __popcll(Ms[0]), p1 = __popcll(Ms[1]);
            int p2 = __popcll(Ms[2]), p3 = __popcll(Ms[3]);
            int o1 = p0, o2 = p0 + p1, o3 = p0 + p1 + p2;
            if (spk2[0] != 0.f) lst2s[nxt][__popcll(Ms[0] & below)]      = c0;
            if (spk2[1] != 0.f) lst2s[nxt][o1 + __popcll(Ms[1] & below)] = c0 + 1;
            if (spk2[2] != 0.f) lst2s[nxt][o2 + __popcll(Ms[2] & below)] = c0 + 2;
            if (spk2[3] != 0.f) lst2s[nxt][o3 + __popcll(Ms[3] & below)] = c0 + 3;
            t2c = o3 + p3;
        } else {
            t2c = 0;
        }

        // ---- output neuron memo(step i-2) ----
        if (lane < DOUT && i >= 2) {
            memo = memo * alpo + (1.f - alpo) * (bov + ao);
            __builtin_nontemporal_store(memo, MoB + (size_t)(i - 2) * DOUT + lane);
        }

        // DS ops are in-order per wave; the wait makes scatter->next-gather
        // airtight and stops the compiler migrating reads above it.
        asm volatile("s_waitcnt lgkmcnt(0)" ::: "memory");
        xp_cur = xp_nxt;
    }
}

// ---------------------------------------------------------------------------
// soft_k: out[b][h] = Σ_t softmax(Mo[b][t])[h].  One thread per timestep row.
// ---------------------------------------------------------------------------
__global__ __launch_bounds__(256) void soft_k(const float* __restrict__ Mo,
                                              float* __restrict__ out) {
    const int b = blockIdx.x;
    const int t = threadIdx.x;
    __shared__ float sm[TT][DOUT];

    if (t < TT) {
        const float* row = Mo + ((size_t)b * TT + t) * DOUT;
        float v[DOUT];
        #pragma unroll
        for (int k = 0; k < DOUT; k += 4) {
            float4 r = *(const float4*)(row + k);
            v[k] = r.x; v[k + 1] = r.y; v[k + 2] = r.z; v[k + 3] = r.w;
        }
        float mx = v[0];
        #pragma unroll
        for (int j = 1; j < DOUT; ++j) mx = fmaxf(mx, v[j]);
        float s = 0.f;
        #pragma unroll
        for (int j = 0; j < DOUT; ++j) { v[j] = __expf(v[j] - mx); s += v[j]; }
        float inv = 1.0f / s;
        #pragma unroll
        for (int j = 0; j < DOUT; ++j) sm[t][j] = v[j] * inv;
    }
    __syncthreads();
    if (t < DOUT) {
        float acc = 0.f;
        for (int tt = 0; tt < TT; ++tt) acc += sm[tt][t];
        out[b * DOUT + t] = acc;
    }
}

extern "C" void kernel_launch(void* const* d_in, const int* in_sizes, int n_in,
                              void* d_out, int out_size, void* d_ws, size_t ws_size,
                              hipStream_t stream) {
    const float* x          = (const float*)d_in[0];
    const float* w_i2h1     = (const float*)d_in[1];
    const float* w_h12h1    = (const float*)d_in[2];
    const float* w_h12h2    = (const float*)d_in[3];
    const float* w_h22h2    = (const float*)d_in[4];
    const float* w_h2o      = (const float*)d_in[5];
    const float* b_h1       = (const float*)d_in[6];
    const float* b_h2       = (const float*)d_in[7];
    const float* b_o        = (const float*)d_in[8];
    const float* tau_adp_h1 = (const float*)d_in[9];
    const float* tau_adp_h2 = (const float*)d_in[10];
    const float* tau_m_h1   = (const float*)d_in[11];
    const float* tau_m_h2   = (const float*)d_in[12];
    const float* tau_m_o    = (const float*)d_in[13];

    signed char* cws = (signed char*)d_ws;
    short* sws = (short*)d_ws;
    float* fws = (float*)d_ws;
    const signed char* Bh = cws;
    const signed char* Bl = cws + COFF_BL;
    const short* sT11 = sws + SOFF_T11;
    const short* sT12 = sws + SOFF_T12;
    const short* sT22 = sws + SOFF_T22;
    float* wT2o = fws + FOFF_W2O;
    float* Xp   = fws + FOFF_XP;
    float* Mo   = fws + FOFF_MO;

    transpose_all_k<<<N_TRANS / 256, 256, 0, stream>>>(
        w_i2h1, w_h12h1, w_h12h2, w_h22h2, w_h2o, cws, sws, fws);

    xgemm_k<<<(BB * TT) / 32, 256, 0, stream>>>(x, Bh, Bl, b_h1, Xp);

    rec_k<<<BB, 64, 0, stream>>>(Xp, sT11, sT12, sT22, wT2o,
                                 b_h2, b_o, tau_adp_h1, tau_adp_h2,
                                 tau_m_h1, tau_m_h2, tau_m_o, Mo);

    soft_k<<<BB, 256, 0, stream>>>(Mo, (float*)d_out);
}

// Round 15
// 683.794 us; speedup vs baseline: 1.4319x; 1.4319x over previous
//
#include <hip/hip_runtime.h>
#include <cstdint>
#include <cstddef>

#define BB 256
#define TT 250
#define DIN 700
#define H1 256
#define H2 256
#define DOUT 20
#define BJ0 0.01f
#define BETAC 1.8f
#define IQSCALE 3.814697265625e-06f   // 2^-18

typedef float f32x4 __attribute__((ext_vector_type(4)));
typedef int   i32x4 __attribute__((ext_vector_type(4)));

// ---------------------------------------------------------------------------
// Workspace layout (bytes):
//   Bh   [256*704] i8  @ 0         hi8 of q18(w_i2h1), k-pad 700..703 = 0
//   Bl   [256*704] i8  @ 180224    lo8 (q = 256*hi + lo, exact)
//   sT11 [256*256] s16 @ 360448    sT11[d*256+h] = q18(w_h12h1[h][d])
//   sT12 [256*256] s16 @ 491520    q18(w_h12h2[h][d])
//   sT22 [256*256] s16 @ 622592    q18(w_h22h2[h][d])
//   w2o  [256*20]  f32 @ 753664    w2o[j*20+o] = w_h2o[o][j]
//   Xp   [64000*256] f32 @ 774144
//   Mo   [256*250*20] f32 @ 66310144
// ---------------------------------------------------------------------------
#define COFF_BL  180224
#define SOFF_T11 180224
#define SOFF_T12 245760
#define SOFF_T22 311296
#define FOFF_W2O 188416
#define FOFF_XP  193536
#define FOFF_MO  16577536
#define N_TRANS  381952

// LDS-only drain + raw barrier: all cross-thread traffic in rec_k is LDS
// (lists, counters); global loads/stores stay in flight across barriers.
#define BARRIER_LDS() asm volatile("s_waitcnt lgkmcnt(0)\n\ts_barrier" ::: "memory")

__device__ __forceinline__ short q18(float w) {
    float s = w * 262144.0f;
    s = fminf(fmaxf(s, -32767.0f), 32767.0f);
    return (short)__float2int_rn(s);
}

__global__ void transpose_all_k(const float* __restrict__ w_i2h1,
                                const float* __restrict__ w_h12h1,
                                const float* __restrict__ w_h12h2,
                                const float* __restrict__ w_h22h2,
                                const float* __restrict__ w_h2o,
                                signed char* __restrict__ cws,
                                short* __restrict__ sws,
                                float* __restrict__ fws) {
    int i = blockIdx.x * blockDim.x + threadIdx.x;
    if (i < 180224) {               // Bh/Bl: [h=0..255][k=0..703]
        int h = i / 704, k = i - h * 704;
        int q = (k < DIN) ? (int)q18(w_i2h1[h * DIN + k]) : 0;
        q = q > 32639 ? 32639 : (q < -32640 ? -32640 : q);  // keep hi8 in range
        int hi = (q + 128) >> 8;
        int lo = q - (hi << 8);
        cws[i] = (signed char)hi;
        cws[COFF_BL + i] = (signed char)lo;
        return;
    }
    i -= 180224;
    if (i < 65536) { int d = i >> 8, h = i & 255;
        sws[SOFF_T11 + i] = q18(w_h12h1[h * H1 + d]); return; }
    i -= 65536;
    if (i < 65536) { int d = i >> 8, h = i & 255;
        sws[SOFF_T12 + i] = q18(w_h12h2[h * H1 + d]); return; }
    i -= 65536;
    if (i < 65536) { int d = i >> 8, h = i & 255;
        sws[SOFF_T22 + i] = q18(w_h22h2[h * H2 + d]); return; }
    i -= 65536;
    if (i < 5120)  { int j = i / 20, o = i % 20;
        fws[FOFF_W2O + i] = w_h2o[o * H2 + j]; return; }
}

// ---------------------------------------------------------------------------
// xgemm_k: Xp = x @ W^T + b_h1 via two exact i8 MFMA GEMMs (unchanged).
// ---------------------------------------------------------------------------
__global__ __launch_bounds__(256) void xgemm_k(const float* __restrict__ x,
                                               const signed char* __restrict__ Bh,
                                               const signed char* __restrict__ Bl,
                                               const float* __restrict__ b_h1,
                                               float* __restrict__ Xp) {
    const int t    = threadIdx.x;
    const int lane = t & 63;
    const int w    = t >> 6;             // wave 0..3 -> cols [64w, 64w+64)
    const int m0   = blockIdx.x * 32;

    __shared__ __align__(16) signed char Asub[32 * 720];
    __shared__ __align__(16) signed char Bhs[256 * 80];
    __shared__ __align__(16) signed char Bls[256 * 80];

    #pragma unroll
    for (int it = 0; it < 22; ++it) {
        int flat = it * 256 + t;
        int row  = flat / 176;
        int c4   = flat - row * 176;
        unsigned int pk = 0u;
        if (c4 < 175) {
            const float* xr = x + (size_t)(m0 + row) * DIN;
            float4 f = *(const float4*)(xr + (c4 << 2));
            pk = (f.x != 0.f ? 1u : 0u)
               | (f.y != 0.f ? 1u : 0u) << 8
               | (f.z != 0.f ? 1u : 0u) << 16
               | (f.w != 0.f ? 1u : 0u) << 24;
        }
        *(unsigned int*)(Asub + row * 720 + (c4 << 2)) = pk;
    }

    i32x4 acch[2][4], accl[2][4];
    #pragma unroll
    for (int mt = 0; mt < 2; ++mt)
        #pragma unroll
        for (int nt = 0; nt < 4; ++nt) {
            acch[mt][nt] = (i32x4){0, 0, 0, 0};
            accl[mt][nt] = (i32x4){0, 0, 0, 0};
        }

    const int arow  = lane & 15;
    const int kg16  = (lane >> 4) << 4;
    const int bcol0 = w << 6;

    for (int ks = 0; ks < 11; ++ks) {
        __syncthreads();
        #pragma unroll
        for (int it2 = 0; it2 < 4; ++it2) {
            int row = it2 * 64 + (t >> 2);
            int ch  = (t & 3) << 4;
            int go  = row * 704 + ks * 64 + ch;
            *(int4*)(Bhs + row * 80 + ch) = *(const int4*)(Bh + go);
            *(int4*)(Bls + row * 80 + ch) = *(const int4*)(Bl + go);
        }
        __syncthreads();

        const int ko = ks * 64 + kg16;
        i32x4 a0 = *(const i32x4*)(Asub + arow * 720 + ko);
        i32x4 a1 = *(const i32x4*)(Asub + (16 + arow) * 720 + ko);
        #pragma unroll
        for (int nt = 0; nt < 4; ++nt) {
            const int bb = (bcol0 + nt * 16 + arow) * 80 + kg16;
            i32x4 bhf = *(const i32x4*)(Bhs + bb);
            i32x4 blf = *(const i32x4*)(Bls + bb);
            acch[0][nt] = __builtin_amdgcn_mfma_i32_16x16x64_i8(a0, bhf, acch[0][nt], 0, 0, 0);
            acch[1][nt] = __builtin_amdgcn_mfma_i32_16x16x64_i8(a1, bhf, acch[1][nt], 0, 0, 0);
            accl[0][nt] = __builtin_amdgcn_mfma_i32_16x16x64_i8(a0, blf, accl[0][nt], 0, 0, 0);
            accl[1][nt] = __builtin_amdgcn_mfma_i32_16x16x64_i8(a1, blf, accl[1][nt], 0, 0, 0);
        }
    }

    const int crb = (lane >> 4) << 2;
    #pragma unroll
    for (int nt = 0; nt < 4; ++nt) {
        int col = bcol0 + nt * 16 + arow;
        float bias = b_h1[col];
        #pragma unroll
        for (int mt = 0; mt < 2; ++mt) {
            #pragma unroll
            for (int r = 0; r < 4; ++r) {
                int row = m0 + mt * 16 + crb + r;
                int ir = (acch[mt][nt][r] << 8) + accl[mt][nt][r];
                __builtin_nontemporal_store(bias + (float)ir * IQSCALE,
                                            Xp + (size_t)row * H1 + col);
            }
        }
    }
}

// ---------------------------------------------------------------------------
// Gather helpers (8 entries per wait group; count-guarded tail, max read
// offset 252+3 = entry 255 -> always inside the 256-entry zero-init lists).
// ---------------------------------------------------------------------------
__device__ __forceinline__ void add8s(const short* __restrict__ T,
                                      const int* __restrict__ L, int off,
                                      int& acc) {
    int4 ea = *(const int4*)(L + off);
    int4 eb = *(const int4*)(L + off + 4);
    acc += T[ea.x << 8]; acc += T[ea.y << 8];
    acc += T[ea.z << 8]; acc += T[ea.w << 8];
    acc += T[eb.x << 8]; acc += T[eb.y << 8];
    acc += T[eb.z << 8]; acc += T[eb.w << 8];
}

__device__ __forceinline__ void tails(const short* __restrict__ T,
                                      const int* __restrict__ L, int done,
                                      int rem, int& acc) {
    if (rem >= 4) {
        int4 e = *(const int4*)(L + done);
        acc += T[e.x << 8]; acc += T[e.y << 8];
        acc += T[e.z << 8]; acc += T[e.w << 8];
        done += 4; rem -= 4;
    }
    if (rem) {
        int4 e = *(const int4*)(L + done);
        acc += T[e.x << 8];
        if (rem > 1) acc += T[e.y << 8];
        if (rem > 2) acc += T[e.z << 8];
    }
}

__device__ __forceinline__ void add8f(const float* __restrict__ T,
                                      const int* __restrict__ L, int off,
                                      float& acc) {
    int4 ea = *(const int4*)(L + off);
    int4 eb = *(const int4*)(L + off + 4);
    acc += T[ea.x * DOUT]; acc += T[ea.y * DOUT];
    acc += T[ea.z * DOUT]; acc += T[ea.w * DOUT];
    acc += T[eb.x * DOUT]; acc += T[eb.y * DOUT];
    acc += T[eb.z * DOUT]; acc += T[eb.w * DOUT];
}

__device__ __forceinline__ void tailf(const float* __restrict__ T,
                                      const int* __restrict__ L, int done,
                                      int rem, float& acc) {
    if (rem >= 4) {
        int4 e = *(const int4*)(L + done);
        acc += T[e.x * DOUT]; acc += T[e.y * DOUT];
        acc += T[e.z * DOUT]; acc += T[e.w * DOUT];
        done += 4; rem -= 4;
    }
    if (rem) {
        int4 e = *(const int4*)(L + done);
        acc += T[e.x * DOUT];
        if (rem > 1) acc += T[e.y * DOUT];
        if (rem > 2) acc += T[e.z * DOUT];
    }
}

// ---------------------------------------------------------------------------
// rec_k: R9 — the measured optimum of this formulation (rec_k ~350 µs).
//   ONE barrier/iter. Lane owns one column end-to-end:
//   waves 0-3 (L1): ir11 over lst1 from global sT11 (wave-uniform entry ->
//     coalesced 128B row slice); all lanes also walk lst2 over LDS w2o for
//     the output column (value used by lanes<5).
//   waves 4-7 (L2): ir12 over lst1 (global sT12) + ir22 over lst2 (LDS).
//   Lists: double-buffered, atomic-compacted; counters: 4-slot rotation
//   (read C[i&3], append C[(i+1)&3], zero C[(i+2)&3]) -- race-free with one
//   barrier. Lists zero-initialized so tail int4 reads are in-bounds and
//   count guards skip stale values.
//   Integer spike path bit-identical (int sums are order-independent).
// LDS: 131072 + 20480 + 2*2048 + 32 = 155,680 B (1 block/CU).
// ---------------------------------------------------------------------------
__global__ __launch_bounds__(512) void rec_k(
    const float* __restrict__ Xp,
    const short* __restrict__ sT11, const short* __restrict__ sT12,
    const short* __restrict__ sT22, const float* __restrict__ wT2o,
    const float* __restrict__ b_h2, const float* __restrict__ b_o,
    const float* __restrict__ tau_adp_h1, const float* __restrict__ tau_adp_h2,
    const float* __restrict__ tau_m_h1, const float* __restrict__ tau_m_h2,
    const float* __restrict__ tau_m_o,
    float* __restrict__ Mo) {
    const int tid  = threadIdx.x;        // 0..511
    const int lane = tid & 63;
    const int w    = tid >> 6;           // wave 0..7
    const bool isL1 = (w < 4);
    const int c    = ((w & 3) << 6) + lane;   // owned column within layer
    const int b    = blockIdx.x;
    const float* __restrict__ XpB = Xp + (size_t)b * TT * H1;
    float* __restrict__ MoB = Mo + (size_t)b * TT * DOUT;

    __shared__ __align__(16) short sT22L[65536];   // 128 KB
    __shared__ __align__(16) float w2oL[5120];     // 20 KB  [j][0..19]
    __shared__ __align__(16) int lst1s[2][256];
    __shared__ __align__(16) int lst2s[2][256];
    __shared__ int lcnt[4][2];                     // 4-slot rotation

    // one-time staging
    {
        const int* src = (const int*)sT22;
        int* dst = (int*)sT22L;
        for (int k = tid; k < 32768; k += 512) dst[k] = src[k];
        for (int k = tid; k < 5120; k += 512) w2oL[k] = wT2o[k];
        if (tid < 256) { lst1s[0][tid] = 0; lst1s[1][tid] = 0;
                         lst2s[0][tid] = 0; lst2s[1][tid] = 0; }
        if (tid < 8) ((int*)lcnt)[tid] = 0;
    }

    // per-lane constants (one layer each)
    float alpha, rr, inb = 0.f;
    if (isL1) {
        alpha = expf(-1.0f / tau_m_h1[c]);
        rr    = expf(-1.0f / tau_adp_h1[c]);
    } else {
        alpha = expf(-1.0f / tau_m_h2[c]);
        rr    = expf(-1.0f / tau_adp_h2[c]);
        inb   = b_h2[c];
    }
    const int oc  = ((w & 3) * 5) + lane;          // output col (L1 lanes<5)
    const int ocs = (isL1 && lane < 5) ? oc : 0;
    float alpo = 0.f, bov = 0.f;
    if (isL1 && lane < 5) { alpo = expf(-1.0f / tau_m_o[oc]); bov = b_o[oc]; }

    float mem = 0.f, spk = 0.f, bbv = BJ0;
    float memo = 0.f;

    float xp_cur = 0.f;
    if (isL1) xp_cur = __builtin_nontemporal_load(XpB + c);
    __syncthreads();                       // staging complete (full drain, once)

    for (int i = 0; i <= TT + 1; ++i) {
        const int cur = i & 1, nxt = cur ^ 1;
        const int cc = i & 3, cn = (i + 1) & 3, cz = (i + 2) & 3;

        const int tot1 = lcnt[cc][0];
        const int tot2 = lcnt[cc][1];
        if (tid == 0) { lcnt[cz][0] = 0; lcnt[cz][1] = 0; }

        float xp_nxt = 0.f;
        if (isL1 && i + 1 < TT)
            xp_nxt = __builtin_nontemporal_load(XpB + (size_t)(i + 1) * H1 + c);

        const int* __restrict__ L1l = lst1s[cur];
        const int* __restrict__ L2l = lst2s[cur];

        int acc1 = 0, acc2 = 0;
        float ao = 0.f;

        if (isL1) {
            if (i < TT) {                          // ir11 over lst1 (global)
                const short* colT = sT11 + c;
                int nb8 = tot1 >> 3;
                for (int kk = 0; kk < nb8; ++kk) add8s(colT, L1l, kk << 3, acc1);
                tails(colT, L1l, nb8 << 3, tot1 & 7, acc1);
            }
            if (i >= 2) {                          // output gather over lst2 (LDS)
                const float* colO = w2oL + ocs;
                int nb8 = tot2 >> 3;
                for (int kk = 0; kk < nb8; ++kk) add8f(colO, L2l, kk << 3, ao);
                tailf(colO, L2l, nb8 << 3, tot2 & 7, ao);
            }
        } else if (i >= 1 && i <= TT) {
            {                                      // ir12 over lst1 (global)
                const short* colT = sT12 + c;
                int nb8 = tot1 >> 3;
                for (int kk = 0; kk < nb8; ++kk) add8s(colT, L1l, kk << 3, acc1);
                tails(colT, L1l, nb8 << 3, tot1 & 7, acc1);
            }
            {                                      // ir22 over lst2 (LDS)
                const short* colL = sT22L + c;
                int nb8 = tot2 >> 3;
                for (int kk = 0; kk < nb8; ++kk) add8s(colL, L2l, kk << 3, acc2);
                tails(colL, L2l, nb8 << 3, tot2 & 7, acc2);
            }
        }

        // ---- update + append (in-registers, per-wave) ----
        if (isL1) {
            if (i < TT) {
                float r1 = (float)acc1 * IQSCALE;
                bbv = rr * bbv + BETAC * (1.f - rr) * spk;
                mem = mem * alpha - bbv * spk + (1.f - alpha) * (xp_cur + r1);
                float ns = (mem - bbv - BJ0) > 0.f ? 1.f : 0.f;
                spk = ns;
                unsigned long long m = __ballot(ns != 0.f ? 1 : 0);
                int base = 0;
                if (lane == 0) base = atomicAdd(&lcnt[cn][0], __popcll(m));
                base = __shfl(base, 0);
                if (ns != 0.f)
                    lst1s[nxt][base + __popcll(m & ((1ull << lane) - 1ull))] = c;
            }
            if (lane < 5 && i >= 2) {
                memo = memo * alpo + (1.f - alpo) * (bov + ao);
                __builtin_nontemporal_store(memo, MoB + (size_t)(i - 2) * DOUT + oc);
            }
        } else if (i >= 1 && i <= TT) {
            float r23 = (float)(acc1 + acc2) * IQSCALE;
            bbv = rr * bbv + BETAC * (1.f - rr) * spk;
            mem = mem * alpha - bbv * spk + (1.f - alpha) * (inb + r23);
            float ns = (mem - bbv - BJ0) > 0.f ? 1.f : 0.f;
            spk = ns;
            unsigned long long m = __ballot(ns != 0.f ? 1 : 0);
            int base = 0;
            if (lane == 0) base = atomicAdd(&lcnt[cn][1], __popcll(m));
            base = __shfl(base, 0);
            if (ns != 0.f)
                lst2s[nxt][base + __popcll(m & ((1ull << lane) - 1ull))] = c;
        }

        BARRIER_LDS();                             // lists + counters published
        xp_cur = xp_nxt;
    }
}

// ---------------------------------------------------------------------------
// soft_k: out[b][h] = Σ_t softmax(Mo[b][t])[h].  One thread per timestep row.
// ---------------------------------------------------------------------------
__global__ __launch_bounds__(256) void soft_k(const float* __restrict__ Mo,
                                              float* __restrict__ out) {
    const int b = blockIdx.x;
    const int t = threadIdx.x;
    __shared__ float sm[TT][DOUT];

    if (t < TT) {
        const float* row = Mo + ((size_t)b * TT + t) * DOUT;
        float v[DOUT];
        #pragma unroll
        for (int k = 0; k < DOUT; k += 4) {
            float4 r = *(const float4*)(row + k);
            v[k] = r.x; v[k + 1] = r.y; v[k + 2] = r.z; v[k + 3] = r.w;
        }
        float mx = v[0];
        #pragma unroll
        for (int j = 1; j < DOUT; ++j) mx = fmaxf(mx, v[j]);
        float s = 0.f;
        #pragma unroll
        for (int j = 0; j < DOUT; ++j) { v[j] = __expf(v[j] - mx); s += v[j]; }
        float inv = 1.0f / s;
        #pragma unroll
        for (int j = 0; j < DOUT; ++j) sm[t][j] = v[j] * inv;
    }
    __syncthreads();
    if (t < DOUT) {
        float acc = 0.f;
        for (int tt = 0; tt < TT; ++tt) acc += sm[tt][t];
        out[b * DOUT + t] = acc;
    }
}

extern "C" void kernel_launch(void* const* d_in, const int* in_sizes, int n_in,
                              void* d_out, int out_size, void* d_ws, size_t ws_size,
                              hipStream_t stream) {
    const float* x          = (const float*)d_in[0];
    const float* w_i2h1     = (const float*)d_in[1];
    const float* w_h12h1    = (const float*)d_in[2];
    const float* w_h12h2    = (const float*)d_in[3];
    const float* w_h22h2    = (const float*)d_in[4];
    const float* w_h2o      = (const float*)d_in[5];
    const float* b_h1       = (const float*)d_in[6];
    const float* b_h2       = (const float*)d_in[7];
    const float* b_o        = (const float*)d_in[8];
    const float* tau_adp_h1 = (const float*)d_in[9];
    const float* tau_adp_h2 = (const float*)d_in[10];
    const float* tau_m_h1   = (const float*)d_in[11];
    const float* tau_m_h2   = (const float*)d_in[12];
    const float* tau_m_o    = (const float*)d_in[13];

    signed char* cws = (signed char*)d_ws;
    short* sws = (short*)d_ws;
    float* fws = (float*)d_ws;
    const signed char* Bh = cws;
    const signed char* Bl = cws + COFF_BL;
    const short* sT11 = sws + SOFF_T11;
    const short* sT12 = sws + SOFF_T12;
    const short* sT22 = sws + SOFF_T22;
    float* wT2o = fws + FOFF_W2O;
    float* Xp   = fws + FOFF_XP;
    float* Mo   = fws + FOFF_MO;

    transpose_all_k<<<N_TRANS / 256, 256, 0, stream>>>(
        w_i2h1, w_h12h1, w_h12h2, w_h22h2, w_h2o, cws, sws, fws);

    xgemm_k<<<(BB * TT) / 32, 256, 0, stream>>>(x, Bh, Bl, b_h1, Xp);

    rec_k<<<BB, 512, 0, stream>>>(Xp, sT11, sT12, sT22, wT2o,
                                  b_h2, b_o, tau_adp_h1, tau_adp_h2,
                                  tau_m_h1, tau_m_h2, tau_m_o, Mo);

    soft_k<<<BB, 256, 0, stream>>>(Mo, (float*)d_out);
}